// Round 9
// baseline (242.286 us; speedup 1.0000x reference)
//
#include <hip/hip_runtime.h>
#include <cmath>

#define BATCH_ 16
#define SN_ 1024
#define DN_ 1024

constexpr float EPS_ = 1e-3f;

typedef unsigned short ushort;
typedef __attribute__((ext_vector_type(8))) short short8;
typedef __attribute__((ext_vector_type(8))) unsigned short ushort8;
typedef __attribute__((ext_vector_type(16))) float f32x16;

__device__ __forceinline__ ushort f2b(float f) {
    unsigned u = __float_as_uint(f);
    unsigned r = (u + 0x7fffu + ((u >> 16) & 1u)) >> 16;
    return (ushort)r;
}

__device__ __forceinline__ void gload16(const void* g, void* l) {
    __builtin_amdgcn_global_load_lds(
        (const __attribute__((address_space(1))) void*)g,
        (__attribute__((address_space(3))) void*)l, 16, 0, 0);
}

#define SCHED0 __builtin_amdgcn_sched_barrier(0)
#define MFMA32(a, b, c) __builtin_amdgcn_mfma_f32_32x32x16_bf16(a, b, c, 0, 0, 0)

// ---------------------------------------------------------------------------
// bf16 MFMA GEMM, 256x256 tile, BK=64, 512 thr (8 waves, 2Mx4N, wave tile
// 128x64 = 4x2 of 32x32), v_mfma_f32_32x32x16_bf16, double-buffered 128 KiB
// LDS, 256-B physical-row pair-packed swizzle (conflict-light, r8-verified):
//   prow = row>>1, slot = (c + 8*(row&1)) ^ (prow&15), byte = prow*256+slot*16
// DMA staging dest linear (t*16), global source pre-swizzled (both-sides).
// K-loop: depth-1 REGISTER PIPELINE across 4 k-phases — phase p issues the
// ds_reads for phase p+1's fragments (alternate named reg set: pA/pB vs
// qA/qB), then runs phase p's 8-MFMA cluster; read latency hides under the
// previous MFMA cluster. No intra-tile sched_barriers (compiler emits
// fine-grained lgkmcnt). Staging for tile t+1 issued alongside phases 0/1.
// One vmcnt(0)+s_barrier per tile boundary (all-waves DMA-landed guarantee);
// only phase-0's read latency is exposed per tile.
// A row-major [M][K], B in B^T layout [N][K], K = 1024.
// MODE 4: bf16 out plain (Mt)
// MODE 5: bf16 out + per-block column sum/sumsq -> psum/psq[by][1024]  (y)
// MODE 6: merged projections, 3-way epilogue by n-block:
//         which=0 -> Qp (bf16, row-scale gamma^s)
//         which=1 -> Kt (bf16, transposed, scale gamma^-s)
//         which=2 -> Vt (bf16, transposed)
// ---------------------------------------------------------------------------
template<int MODE>
__global__ __launch_bounds__(512, 2)
void gemm_bf(const ushort* __restrict__ A0, const ushort* __restrict__ B0,
             void* __restrict__ C0, void* __restrict__ C1, void* __restrict__ C2,
             float* __restrict__ psum, float* __restrict__ psq,
             long sA, long sB, long sBm, long sC, float coef)
{
    __shared__ __align__(16) char lds[131072];  // 2 bufs x (A 32K + B 32K)

    // ---- bijective XCD swizzle (all grids are multiples of 8 blocks) ----
    const int gx = gridDim.x, gy = gridDim.y;
    int lid   = blockIdx.x + gx * (blockIdx.y + gy * blockIdx.z);
    int total = gx * gy * gridDim.z;
    int swz   = (lid & 7) * (total >> 3) + (lid >> 3);
    int bx = swz % gx;
    int rest = swz / gx;
    int by = rest % gy;
    int bz = rest / gy;

    const int m0 = by * 256, n0 = bx * 256;
    const ushort* A  = A0 + (long)bz * sA;
    const ushort* Bp = B0 + (long)bz * sB + (long)(m0 >> 10) * sBm;

    const int t = threadIdx.x;
    const int l = t & 63, w = t >> 6;
    const int wr = w >> 2, wc = w & 3;    // wave grid 2M x 4N
    const int ln = l & 31;                // MFMA row/col lane
    const int kb = l >> 5;                // k half (0/1)
    const int lsh   = ln >> 1;            // prow part of lane
    const int lodd8 = (ln & 1) * 8;       // row-parity slot offset

    // frag-read lane bases (byte offsets inside a buffer)
    const int aOff = wr * 16384 + lsh * 256;            // + mi*4096 + sxp
    const int bOff = 32768 + wc * 8192 + lsh * 256;     // + nj*4096 + sxp

    // ---- staging: thread t writes 16B at linear LDS t*16; global source
    //      pre-swizzled per the 256-B-row mapping above.
    const int su = (t & 15) ^ ((t >> 4) & 15);
    const int sc = su & 7;                        // logical chunk
    const int srow = 2 * (t >> 4) + (su >> 3);    // logical row (h=0)
    const ushort* gA = A  + (long)(m0 + srow) * 1024 + sc * 8;
    const ushort* gB = Bp + (long)(n0 + srow) * 1024 + sc * 8;
    char* lA = lds + t * 16;                 // + buf + h*8192
    char* lB = lds + 32768 + t * 16;

#define STA(h, k0, bo_) gload16(gA + (long)(h) * 65536 + (k0), lA + (bo_) + (h) * 8192)
#define STB(h, k0, bo_) gload16(gB + (long)(h) * 65536 + (k0), lB + (bo_) + (h) * 8192)

#define RDF(FA, FB, BASEP, KK) do {                                        \
    const int sxp_ = ((((KK) * 2 + kb) + lodd8) ^ lsh) * 16;               \
    FA[0] = *(const short8*)((BASEP) + aOff + 0 * 4096 + sxp_);            \
    FA[1] = *(const short8*)((BASEP) + aOff + 1 * 4096 + sxp_);            \
    FA[2] = *(const short8*)((BASEP) + aOff + 2 * 4096 + sxp_);            \
    FA[3] = *(const short8*)((BASEP) + aOff + 3 * 4096 + sxp_);            \
    FB[0] = *(const short8*)((BASEP) + bOff + 0 * 4096 + sxp_);            \
    FB[1] = *(const short8*)((BASEP) + bOff + 1 * 4096 + sxp_);            \
} while (0)

#define MM8(FA, FB) do {                                                   \
    __builtin_amdgcn_s_setprio(1);                                         \
    acc[0][0] = MFMA32(FA[0], FB[0], acc[0][0]);                           \
    acc[0][1] = MFMA32(FA[0], FB[1], acc[0][1]);                           \
    acc[1][0] = MFMA32(FA[1], FB[0], acc[1][0]);                           \
    acc[1][1] = MFMA32(FA[1], FB[1], acc[1][1]);                           \
    acc[2][0] = MFMA32(FA[2], FB[0], acc[2][0]);                           \
    acc[2][1] = MFMA32(FA[2], FB[1], acc[2][1]);                           \
    acc[3][0] = MFMA32(FA[3], FB[0], acc[3][0]);                           \
    acc[3][1] = MFMA32(FA[3], FB[1], acc[3][1]);                           \
    __builtin_amdgcn_s_setprio(0);                                         \
} while (0)

    f32x16 acc[4][2] = {};

    // ---- prologue: stage tile 0 into buf 0 ----
    STB(0, 0, 0); STB(1, 0, 0); STB(2, 0, 0); STB(3, 0, 0);
    STA(0, 0, 0); STA(1, 0, 0); STA(2, 0, 0); STA(3, 0, 0);
    SCHED0;
    asm volatile("s_waitcnt vmcnt(0)" ::: "memory");
    SCHED0;
    __builtin_amdgcn_s_barrier();
    SCHED0;

    short8 pA[4], pB[2], qA[4], qB[2];
    RDF(pA, pB, lds, 0);                 // phase-0 frags of tile 0

    for (int kt = 0; kt < 16; ++kt) {
        const char* base  = lds + ((kt & 1) << 16);
        const char* nbase = lds + (((kt + 1) & 1) << 16);
        const int bn = ((kt + 1) & 1) << 16;
        const int k1 = (kt + 1) << 6;
        const bool st = kt < 15;

        // phase 0: compute p-frags, prefetch phase-1 frags + B staging
        RDF(qA, qB, base, 1);
        if (st) { STB(0, k1, bn); STB(1, k1, bn); STB(2, k1, bn); STB(3, k1, bn); }
        MM8(pA, pB);

        // phase 1: compute q-frags, prefetch phase-2 frags + A staging
        RDF(pA, pB, base, 2);
        if (st) { STA(0, k1, bn); STA(1, k1, bn); STA(2, k1, bn); STA(3, k1, bn); }
        MM8(qA, qB);

        // phase 2: compute p-frags, prefetch phase-3 frags
        RDF(qA, qB, base, 3);
        MM8(pA, pB);

        // phase 3: compute q-frags (no prefetch: next buf not ready)
        MM8(qA, qB);

        // tile boundary: own staging landed; barrier -> all waves' staging landed
        asm volatile("s_waitcnt vmcnt(0)" ::: "memory");
        __builtin_amdgcn_s_barrier();
        SCHED0;
        if (st) RDF(pA, pB, nbase, 0);   // phase-0 frags of next tile
    }

    // C/D 32x32 layout: col = ln, row = (reg&3) + 8*(reg>>2) + 4*kb
    // ---------------- epilogues ----------------
    if constexpr (MODE == 4) {
        ushort* C = (ushort*)C0 + (long)bz * sC;
#pragma unroll
        for (int mi = 0; mi < 4; ++mi)
#pragma unroll
            for (int reg = 0; reg < 16; ++reg) {
                int row = m0 + wr * 128 + mi * 32 + (reg & 3) + 8 * (reg >> 2) + 4 * kb;
#pragma unroll
                for (int nj = 0; nj < 2; ++nj)
                    C[(long)row * 1024 + n0 + wc * 64 + nj * 32 + ln] =
                        f2b(acc[mi][nj][reg]);
            }
    } else if constexpr (MODE == 5) {
        // bf16 y out + per-block column sums/sumsq (fused GroupNorm stats)
        ushort* C = (ushort*)C0;
        float cs0 = 0.f, cq0 = 0.f, cs1 = 0.f, cq1 = 0.f;
#pragma unroll
        for (int mi = 0; mi < 4; ++mi)
#pragma unroll
            for (int reg = 0; reg < 16; ++reg) {
                float v0 = acc[mi][0][reg], v1 = acc[mi][1][reg];
                cs0 += v0; cq0 += v0 * v0;
                cs1 += v1; cq1 += v1 * v1;
                int row = m0 + wr * 128 + mi * 32 + (reg & 3) + 8 * (reg >> 2) + 4 * kb;
                C[(long)row * 1024 + n0 + wc * 64 + ln]      = f2b(v0);
                C[(long)row * 1024 + n0 + wc * 64 + 32 + ln] = f2b(v1);
            }
        float* S4 = (float*)lds;            // [256 cols][4]
        float* Q4 = (float*)(lds + 4096);
        {
            int c0i = wc * 64 + ln, c1i = wc * 64 + 32 + ln, idx = wr * 2 + kb;
            S4[c0i * 4 + idx] = cs0; S4[c1i * 4 + idx] = cs1;
            Q4[c0i * 4 + idx] = cq0; Q4[c1i * 4 + idx] = cq1;
        }
        __syncthreads();
        if (t < 256) {
            float s = S4[t * 4] + S4[t * 4 + 1] + S4[t * 4 + 2] + S4[t * 4 + 3];
            float q = Q4[t * 4] + Q4[t * 4 + 1] + Q4[t * 4 + 2] + Q4[t * 4 + 3];
            psum[(long)by * 1024 + n0 + t] = s;
            psq [(long)by * 1024 + n0 + t] = q;
        }
    } else {
        // MODE 6: merged projections
        const int which = n0 >> 10;       // 0=Q, 1=K, 2=V
        const int nq = n0 & 1023;
        if (which == 0) {
            ushort* C = (ushort*)C0;
#pragma unroll
            for (int mi = 0; mi < 4; ++mi)
#pragma unroll
                for (int reg = 0; reg < 16; ++reg) {
                    int row = m0 + wr * 128 + mi * 32 + (reg & 3) + 8 * (reg >> 2) + 4 * kb;
                    float s = exp2f(coef * (float)(row & 1023));
#pragma unroll
                    for (int nj = 0; nj < 2; ++nj)
                        C[(long)row * 1024 + nq + wc * 64 + nj * 32 + ln] =
                            f2b(acc[mi][nj][reg] * s);
                }
        } else {
            // transposed store via LDS bounce (slot = chunk ^ (cn&31)),
            // fully coalesced ushort8 readout. out[b][d][s]
            ushort* Tl = (ushort*)lds;
            const int bb = m0 >> 10;          // batch index
            const int ms = m0 & 1023;         // s-offset within batch
            ushort* Ct = (ushort*)((which == 1) ? C1 : C2) + (long)bb * sC;
            const float cf = (which == 1) ? -coef : 0.0f;
            __syncthreads();
#pragma unroll
            for (int mi = 0; mi < 4; ++mi)
#pragma unroll
                for (int reg = 0; reg < 16; ++reg) {
                    int rm = wr * 128 + mi * 32 + (reg & 3) + 8 * (reg >> 2) + 4 * kb;
                    float s = exp2f(cf * (float)(ms + rm));
#pragma unroll
                    for (int nj = 0; nj < 2; ++nj) {
                        int cn = wc * 64 + nj * 32 + ln;
                        int p  = (rm >> 3) ^ (cn & 31);
                        Tl[cn * 256 + p * 8 + (rm & 7)] = f2b(acc[mi][nj][reg] * s);
                    }
                }
            __syncthreads();
#pragma unroll
            for (int it = 0; it < 16; ++it) {
                int cn = (t >> 5) + it * 16;
                int ch = t & 31;
                int p  = ch ^ (cn & 31);
                ushort8 v = *(const ushort8*)&Tl[cn * 256 + p * 8];
                *(ushort8*)&Ct[(long)(nq + cn) * 1024 + ms + ch * 8] = v;
            }
        }
    }
#undef STA
#undef STB
#undef RDF
#undef MM8
}

// ---------------- prepass: fp32 -> bf16 convert ----------------
__global__ __launch_bounds__(256)
void conv_x_k(const float* __restrict__ x, ushort* __restrict__ xb)
{
    long i = ((long)blockIdx.x * 256 + threadIdx.x) * 8;
    float4 a = *(const float4*)&x[i];
    float4 b = *(const float4*)&x[i + 4];
    ushort8 v;
    v[0] = f2b(a.x); v[1] = f2b(a.y); v[2] = f2b(a.z); v[3] = f2b(a.w);
    v[4] = f2b(b.x); v[5] = f2b(b.y); v[6] = f2b(b.z); v[7] = f2b(b.w);
    *(ushort8*)&xb[i] = v;
}

// ---------------- prepass: weight transpose + convert ----------------
__global__ __launch_bounds__(256)
void wt_k(const float* __restrict__ W, ushort* __restrict__ Wt)
{
    __shared__ float Tl[32][33];
    int tx = threadIdx.x & 31, ty = threadIdx.x >> 5;
    int c0 = blockIdx.x * 32, r0 = blockIdx.y * 32;
#pragma unroll
    for (int i = 0; i < 4; i++)
        Tl[ty + 8 * i][tx] = W[(long)(r0 + ty + 8 * i) * 1024 + c0 + tx];
    __syncthreads();
#pragma unroll
    for (int i = 0; i < 4; i++)
        Wt[(long)(c0 + ty + 8 * i) * 1024 + r0 + tx] = f2b(Tl[tx][ty + 8 * i]);
}

// ---------------- GroupNorm: finalize stats -> fused scale/bias ----------------
__global__ __launch_bounds__(256)
void stats2(const float* __restrict__ psum, const float* __restrict__ psq,
            const float* __restrict__ gsc, const float* __restrict__ gbt,
            float* __restrict__ fs, float* __restrict__ bias)
{
    int d = blockIdx.x * 256 + threadIdx.x;
    int b = blockIdx.y;
    float s = 0.f, q = 0.f;
#pragma unroll
    for (int z = 0; z < 4; z++) {
        long o = ((long)(b * 4 + z) << 10) + d;
        s += psum[o];
        q += psq[o];
    }
    float mean = s * (1.0f / SN_);
    float var  = q * (1.0f / SN_) - mean * mean;
    var = fmaxf(var, 0.0f);
    float rstd = rsqrtf(var + EPS_);
    float f = rstd * gsc[d];
    fs[(long)b * DN_ + d]   = f;
    bias[(long)b * DN_ + d] = gbt[d] - mean * f;
}

// ---------------- normalize: bf16 y -> fp32 out ----------------
__global__ __launch_bounds__(256)
void norm_k(const ushort* __restrict__ yb, const float* __restrict__ fs,
            const float* __restrict__ bias, float* __restrict__ out)
{
    long i = ((long)blockIdx.x * 256 + threadIdx.x) * 8;
    int d = (int)(i & (DN_ - 1));
    int b = (int)(i >> 20);
    ushort8 v = *(const ushort8*)&yb[i];
    long o = (long)b * DN_ + d;
    float4 f0 = *(const float4*)&fs[o];
    float4 f1 = *(const float4*)&fs[o + 4];
    float4 b0 = *(const float4*)&bias[o];
    float4 b1 = *(const float4*)&bias[o + 4];
    float4 o0, o1;
    o0.x = __uint_as_float((unsigned)v[0] << 16) * f0.x + b0.x;
    o0.y = __uint_as_float((unsigned)v[1] << 16) * f0.y + b0.y;
    o0.z = __uint_as_float((unsigned)v[2] << 16) * f0.z + b0.z;
    o0.w = __uint_as_float((unsigned)v[3] << 16) * f0.w + b0.w;
    o1.x = __uint_as_float((unsigned)v[4] << 16) * f1.x + b1.x;
    o1.y = __uint_as_float((unsigned)v[5] << 16) * f1.y + b1.y;
    o1.z = __uint_as_float((unsigned)v[6] << 16) * f1.z + b1.z;
    o1.w = __uint_as_float((unsigned)v[7] << 16) * f1.w + b1.w;
    *(float4*)&out[i]     = o0;
    *(float4*)&out[i + 4] = o1;
}

extern "C" void kernel_launch(void* const* d_in, const int* in_sizes, int n_in,
                              void* d_out, int out_size, void* d_ws, size_t ws_size,
                              hipStream_t stream)
{
    const float* x   = (const float*)d_in[0];
    const float* Wq  = (const float*)d_in[1];
    const float* Wk  = (const float*)d_in[2];
    const float* Wv  = (const float*)d_in[3];
    const float* gsc = (const float*)d_in[4];
    const float* gbt = (const float*)d_in[5];
    float* out = (float*)d_out;

    const long SD = (long)SN_ * DN_;
    const long DD = (long)DN_ * DN_;
    const size_t MB32 = (size_t)SD * BATCH_ * sizeof(ushort);  // 32 MiB

    char* ws = (char*)d_ws;
    ushort* xb  = (ushort*)(ws);            // x bf16; reused as yb after projs
    ushort* Qp  = (ushort*)(ws + 1 * MB32);
    ushort* Kt  = (ushort*)(ws + 2 * MB32);
    ushort* Vt  = (ushort*)(ws + 3 * MB32);
    ushort* Mt  = (ushort*)(ws + 4 * MB32);
    ushort* Wct = (ushort*)(ws + 5 * MB32);                       // [3072][1024] bf16
    float*  psum = (float*)(ws + 5 * MB32 + (6u << 20));          // [64][1024]
    float*  psq  = (float*)(ws + 5 * MB32 + (6u << 20) + (1u << 18));
    float*  fs   = (float*)(ws + 5 * MB32 + (6u << 20) + (2u << 18));
    float*  bias = (float*)(ws + 5 * MB32 + (6u << 20) + (2u << 18) + (1u << 16));
    ushort* yb  = xb;

    const float lgf = (float)log2(0.96875);  // log2(gamma)

    dim3 blk512(512);
    dim3 blk(256);
    dim3 gproj(12, 64);     // N=3072/256, M=16384/256  (768 blocks)
    dim3 gmt(4, 4, 16);     // per-batch 1024x1024      (256 blocks)
    dim3 gy(4, 64);         // N=1024/256, M=16384/256  (256 blocks)

    // prepass
    conv_x_k<<<dim3(8192), blk, 0, stream>>>(x, xb);
    wt_k<<<dim3(32, 32), blk, 0, stream>>>(Wq, Wct);
    wt_k<<<dim3(32, 32), blk, 0, stream>>>(Wk, Wct + 1024 * 1024);
    wt_k<<<dim3(32, 32), blk, 0, stream>>>(Wv, Wct + 2 * 1024 * 1024);

    // merged projections: Q' (scale gamma^s), K't (transp, gamma^-s), V't (transp)
    gemm_bf<6><<<gproj, blk512, 0, stream>>>(xb, Wct, Qp, Kt, Vt,
                                             nullptr, nullptr,
                                             0, 0, 0, SD, lgf);
    // Mt = V't x Kt(B^T) = M^T   [B][D][D] bf16
    gemm_bf<4><<<gmt, blk512, 0, stream>>>(Vt, Kt, Mt, nullptr, nullptr,
                                           nullptr, nullptr,
                                           SD, SD, 0, DD, 0.0f);
    // y = Q' x Mt(B^T per batch) -> bf16 yb + fused column stats
    gemm_bf<5><<<gy, blk512, 0, stream>>>(Qp, Mt, yb, nullptr, nullptr,
                                          psum, psq,
                                          0, 0, DD, 0, 0.0f);

    // GroupNorm finalize + apply
    stats2<<<dim3(4, 16), blk, 0, stream>>>(psum, psq, gsc, gbt, fs, bias);
    norm_k<<<dim3(8192), blk, 0, stream>>>(yb, fs, bias, out);
}

// Round 10
// 241.605 us; speedup vs baseline: 1.0028x; 1.0028x over previous
//
#include <hip/hip_runtime.h>
#include <cmath>

#define BATCH_ 16
#define SN_ 1024
#define DN_ 1024

constexpr float EPS_ = 1e-3f;

typedef unsigned short ushort;
typedef __attribute__((ext_vector_type(8))) short short8;
typedef __attribute__((ext_vector_type(8))) unsigned short ushort8;
typedef __attribute__((ext_vector_type(16))) float f32x16;

__device__ __forceinline__ ushort f2b(float f) {
    unsigned u = __float_as_uint(f);
    unsigned r = (u + 0x7fffu + ((u >> 16) & 1u)) >> 16;
    return (ushort)r;
}

__device__ __forceinline__ void gload16(const void* g, void* l) {
    __builtin_amdgcn_global_load_lds(
        (const __attribute__((address_space(1))) void*)g,
        (__attribute__((address_space(3))) void*)l, 16, 0, 0);
}

#define SCHED0 __builtin_amdgcn_sched_barrier(0)
#define MFMA32(a, b, c) __builtin_amdgcn_mfma_f32_32x32x16_bf16(a, b, c, 0, 0, 0)

// ---------------------------------------------------------------------------
// bf16 MFMA GEMM, 256x256 tile, BK=64, 256 thr (4 waves, 2Mx2N, wave tile
// 128x128 = 4x4 of 32x32) — HIGH-ILP config: each frag read feeds 4 MFMAs,
// halving CU-wide LDS port traffic (128 b128 reads/K-tile ~= matrix time).
// acc = 16 x f32x16 = 256 VGPR -> 1 wave/SIMD; latency hidden by ILP (no
// intra-tile sched barriers: compiler hoists next-phase ds_reads under the
// 16-deep independent MFMA clusters).
// Double-buffered 128 KiB LDS, 256-B physical-row pair-packed swizzle
// (conflict-free, r8-verified):
//   prow = row>>1, slot = (c + 8*(row&1)) ^ (prow&15), byte = prow*256+slot*16
// DMA staging dest linear (t*16), global source pre-swizzled (both-sides).
// Staging for tile t+1 issued in k-phases 0 (B) and 1 (A); one
// vmcnt(0)+s_barrier per tile boundary (DMA age ~1500cy > HBM latency).
// A row-major [M][K], B in B^T layout [N][K], K = 1024.
// MODE 4: bf16 out plain (Mt)
// MODE 5: bf16 out + per-block column sum/sumsq -> psum/psq[by][1024]  (y)
// MODE 6: merged projections, 3-way epilogue by n-block:
//         which=0 -> Qp (bf16, row-scale gamma^s)
//         which=1 -> Kt (bf16, transposed, scale gamma^-s)
//         which=2 -> Vt (bf16, transposed)
// ---------------------------------------------------------------------------
template<int MODE>
__global__ __launch_bounds__(256, 1)
void gemm_bf(const ushort* __restrict__ A0, const ushort* __restrict__ B0,
             void* __restrict__ C0, void* __restrict__ C1, void* __restrict__ C2,
             float* __restrict__ psum, float* __restrict__ psq,
             long sA, long sB, long sBm, long sC, float coef)
{
    __shared__ __align__(16) char lds[131072];  // 2 bufs x (A 32K + B 32K)

    // ---- bijective XCD swizzle (all grids are multiples of 8 blocks) ----
    const int gx = gridDim.x, gy = gridDim.y;
    int lid   = blockIdx.x + gx * (blockIdx.y + gy * blockIdx.z);
    int total = gx * gy * gridDim.z;
    int swz   = (lid & 7) * (total >> 3) + (lid >> 3);
    int bx = swz % gx;
    int rest = swz / gx;
    int by = rest % gy;
    int bz = rest / gy;

    const int m0 = by * 256, n0 = bx * 256;
    const ushort* A  = A0 + (long)bz * sA;
    const ushort* Bp = B0 + (long)bz * sB + (long)(m0 >> 10) * sBm;

    const int t = threadIdx.x;
    const int l = t & 63, w = t >> 6;     // 4 waves
    const int wr = w >> 1, wc = w & 1;    // wave grid 2M x 2N
    const int ln = l & 31;                // MFMA row/col lane
    const int kb = l >> 5;                // k half (0/1)
    const int lsh   = ln >> 1;            // prow part of lane
    const int lodd8 = (ln & 1) * 8;       // row-parity slot offset

    // frag-read lane bases (byte offsets inside a buffer)
    const int aOff = wr * 16384 + lsh * 256;            // + mi*4096 + sxp
    const int bOff = 32768 + wc * 16384 + lsh * 256;    // + nj*4096 + sxp

    // ---- staging: thread t writes 16B at linear LDS t*16; global source
    //      pre-swizzled per the 256-B-row mapping. 256 thr x 16B = 4KB/issue
    //      = 32 logical rows; 8 issues per matrix per tile.
    const int su = (t & 15) ^ (t >> 4);
    const int sc = su & 7;                        // logical chunk
    const int srow = 2 * (t >> 4) + (su >> 3);    // logical row (issue 0)
    const ushort* gA = A  + (long)(m0 + srow) * 1024 + sc * 8;
    const ushort* gB = Bp + (long)(n0 + srow) * 1024 + sc * 8;
    char* lA = lds + t * 16;                 // + buf + h*4096
    char* lB = lds + 32768 + t * 16;

#define STA(h, k0, bo_) gload16(gA + (long)(h) * 32768 + (k0), lA + (bo_) + (h) * 4096)
#define STB(h, k0, bo_) gload16(gB + (long)(h) * 32768 + (k0), lB + (bo_) + (h) * 4096)
#define STA8(k0, bo_) do { STA(0,k0,bo_); STA(1,k0,bo_); STA(2,k0,bo_); STA(3,k0,bo_); \
                           STA(4,k0,bo_); STA(5,k0,bo_); STA(6,k0,bo_); STA(7,k0,bo_); } while (0)
#define STB8(k0, bo_) do { STB(0,k0,bo_); STB(1,k0,bo_); STB(2,k0,bo_); STB(3,k0,bo_); \
                           STB(4,k0,bo_); STB(5,k0,bo_); STB(6,k0,bo_); STB(7,k0,bo_); } while (0)

    f32x16 acc[4][4] = {};

    // ---- prologue: stage tile 0 into buf 0 ----
    STB8(0, 0);
    STA8(0, 0);
    SCHED0;
    asm volatile("s_waitcnt vmcnt(0)" ::: "memory");
    SCHED0;
    __builtin_amdgcn_s_barrier();
    SCHED0;

    for (int kt = 0; kt < 16; ++kt) {
        const char* base = lds + ((kt & 1) << 16);
        const int bn = ((kt + 1) & 1) << 16;
        const int k1 = (kt + 1) << 6;
        const bool st = kt < 15;

#pragma unroll
        for (int ks = 0; ks < 4; ++ks) {
            const int sxp = (((ks * 2 + kb) + lodd8) ^ lsh) * 16;
            short8 fa0 = *(const short8*)(base + aOff + 0 * 4096 + sxp);
            short8 fa1 = *(const short8*)(base + aOff + 1 * 4096 + sxp);
            short8 fa2 = *(const short8*)(base + aOff + 2 * 4096 + sxp);
            short8 fa3 = *(const short8*)(base + aOff + 3 * 4096 + sxp);
            short8 fb0 = *(const short8*)(base + bOff + 0 * 4096 + sxp);
            short8 fb1 = *(const short8*)(base + bOff + 1 * 4096 + sxp);
            short8 fb2 = *(const short8*)(base + bOff + 2 * 4096 + sxp);
            short8 fb3 = *(const short8*)(base + bOff + 3 * 4096 + sxp);
            if (st) {
                if (ks == 0) STB8(k1, bn);
                else if (ks == 1) STA8(k1, bn);
            }
            __builtin_amdgcn_s_setprio(1);
            acc[0][0] = MFMA32(fa0, fb0, acc[0][0]);
            acc[0][1] = MFMA32(fa0, fb1, acc[0][1]);
            acc[0][2] = MFMA32(fa0, fb2, acc[0][2]);
            acc[0][3] = MFMA32(fa0, fb3, acc[0][3]);
            acc[1][0] = MFMA32(fa1, fb0, acc[1][0]);
            acc[1][1] = MFMA32(fa1, fb1, acc[1][1]);
            acc[1][2] = MFMA32(fa1, fb2, acc[1][2]);
            acc[1][3] = MFMA32(fa1, fb3, acc[1][3]);
            acc[2][0] = MFMA32(fa2, fb0, acc[2][0]);
            acc[2][1] = MFMA32(fa2, fb1, acc[2][1]);
            acc[2][2] = MFMA32(fa2, fb2, acc[2][2]);
            acc[2][3] = MFMA32(fa2, fb3, acc[2][3]);
            acc[3][0] = MFMA32(fa3, fb0, acc[3][0]);
            acc[3][1] = MFMA32(fa3, fb1, acc[3][1]);
            acc[3][2] = MFMA32(fa3, fb2, acc[3][2]);
            acc[3][3] = MFMA32(fa3, fb3, acc[3][3]);
            __builtin_amdgcn_s_setprio(0);
        }
        // tile boundary: own prefetch landed + all waves done reading base
        asm volatile("s_waitcnt vmcnt(0)" ::: "memory");
        SCHED0;
        __builtin_amdgcn_s_barrier();
        SCHED0;
    }

    // C/D 32x32 layout: col = ln, row = (reg&3) + 8*(reg>>2) + 4*kb
    // ---------------- epilogues ----------------
    if constexpr (MODE == 4) {
        ushort* C = (ushort*)C0 + (long)bz * sC;
#pragma unroll
        for (int mi = 0; mi < 4; ++mi)
#pragma unroll
            for (int reg = 0; reg < 16; ++reg) {
                int row = m0 + wr * 128 + mi * 32 + (reg & 3) + 8 * (reg >> 2) + 4 * kb;
#pragma unroll
                for (int nj = 0; nj < 4; ++nj)
                    C[(long)row * 1024 + n0 + wc * 128 + nj * 32 + ln] =
                        f2b(acc[mi][nj][reg]);
            }
    } else if constexpr (MODE == 5) {
        // bf16 y out + per-block column sums/sumsq (fused GroupNorm stats)
        ushort* C = (ushort*)C0;
        float cs[4] = {0.f, 0.f, 0.f, 0.f}, cq[4] = {0.f, 0.f, 0.f, 0.f};
#pragma unroll
        for (int mi = 0; mi < 4; ++mi)
#pragma unroll
            for (int reg = 0; reg < 16; ++reg) {
                int row = m0 + wr * 128 + mi * 32 + (reg & 3) + 8 * (reg >> 2) + 4 * kb;
#pragma unroll
                for (int nj = 0; nj < 4; ++nj) {
                    float v = acc[mi][nj][reg];
                    cs[nj] += v; cq[nj] += v * v;
                    C[(long)row * 1024 + n0 + wc * 128 + nj * 32 + ln] = f2b(v);
                }
            }
        float* S4 = (float*)lds;            // [256 cols][4]
        float* Q4 = (float*)(lds + 4096);
        {
            int idx = wr * 2 + kb;
#pragma unroll
            for (int nj = 0; nj < 4; ++nj) {
                int ci = wc * 128 + nj * 32 + ln;
                S4[ci * 4 + idx] = cs[nj];
                Q4[ci * 4 + idx] = cq[nj];
            }
        }
        __syncthreads();
        {
            float s = S4[t * 4] + S4[t * 4 + 1] + S4[t * 4 + 2] + S4[t * 4 + 3];
            float q = Q4[t * 4] + Q4[t * 4 + 1] + Q4[t * 4 + 2] + Q4[t * 4 + 3];
            psum[(long)by * 1024 + n0 + t] = s;
            psq [(long)by * 1024 + n0 + t] = q;
        }
    } else {
        // MODE 6: merged projections
        const int which = n0 >> 10;       // 0=Q, 1=K, 2=V
        const int nq = n0 & 1023;
        if (which == 0) {
            ushort* C = (ushort*)C0;
#pragma unroll
            for (int mi = 0; mi < 4; ++mi)
#pragma unroll
                for (int reg = 0; reg < 16; ++reg) {
                    int row = m0 + wr * 128 + mi * 32 + (reg & 3) + 8 * (reg >> 2) + 4 * kb;
                    float s = exp2f(coef * (float)(row & 1023));
#pragma unroll
                    for (int nj = 0; nj < 4; ++nj)
                        C[(long)row * 1024 + nq + wc * 128 + nj * 32 + ln] =
                            f2b(acc[mi][nj][reg] * s);
                }
        } else {
            // transposed store via LDS bounce (slot = (rm>>3) ^ (cn&31)),
            // fully coalesced ushort8 readout. out[b][d][s]
            ushort* Tl = (ushort*)lds;
            const int bb = m0 >> 10;          // batch index
            const int ms = m0 & 1023;         // s-offset within batch
            ushort* Ct = (ushort*)((which == 1) ? C1 : C2) + (long)bb * sC;
            const float cf = (which == 1) ? -coef : 0.0f;
            __syncthreads();
#pragma unroll
            for (int mi = 0; mi < 4; ++mi)
#pragma unroll
                for (int reg = 0; reg < 16; ++reg) {
                    int rm = wr * 128 + mi * 32 + (reg & 3) + 8 * (reg >> 2) + 4 * kb;
                    float s = exp2f(cf * (float)(ms + rm));
#pragma unroll
                    for (int nj = 0; nj < 4; ++nj) {
                        int cn = wc * 128 + nj * 32 + ln;
                        int p  = (rm >> 3) ^ (cn & 31);
                        Tl[cn * 256 + p * 8 + (rm & 7)] = f2b(acc[mi][nj][reg] * s);
                    }
                }
            __syncthreads();
#pragma unroll
            for (int it = 0; it < 32; ++it) {
                int cn = it * 8 + (t >> 5);
                int ch = t & 31;
                int p  = ch ^ (cn & 31);
                ushort8 v = *(const ushort8*)&Tl[cn * 256 + p * 8];
                *(ushort8*)&Ct[(long)(nq + cn) * 1024 + ms + ch * 8] = v;
            }
        }
    }
#undef STA
#undef STB
#undef STA8
#undef STB8
}

// ---------------- prepass: fp32 -> bf16 convert ----------------
__global__ __launch_bounds__(256)
void conv_x_k(const float* __restrict__ x, ushort* __restrict__ xb)
{
    long i = ((long)blockIdx.x * 256 + threadIdx.x) * 8;
    float4 a = *(const float4*)&x[i];
    float4 b = *(const float4*)&x[i + 4];
    ushort8 v;
    v[0] = f2b(a.x); v[1] = f2b(a.y); v[2] = f2b(a.z); v[3] = f2b(a.w);
    v[4] = f2b(b.x); v[5] = f2b(b.y); v[6] = f2b(b.z); v[7] = f2b(b.w);
    *(ushort8*)&xb[i] = v;
}

// ---------------- prepass: weight transpose + convert ----------------
__global__ __launch_bounds__(256)
void wt_k(const float* __restrict__ W, ushort* __restrict__ Wt)
{
    __shared__ float Tl[32][33];
    int tx = threadIdx.x & 31, ty = threadIdx.x >> 5;
    int c0 = blockIdx.x * 32, r0 = blockIdx.y * 32;
#pragma unroll
    for (int i = 0; i < 4; i++)
        Tl[ty + 8 * i][tx] = W[(long)(r0 + ty + 8 * i) * 1024 + c0 + tx];
    __syncthreads();
#pragma unroll
    for (int i = 0; i < 4; i++)
        Wt[(long)(c0 + ty + 8 * i) * 1024 + r0 + tx] = f2b(Tl[tx][ty + 8 * i]);
}

// ---------------- GroupNorm: finalize stats -> fused scale/bias ----------------
__global__ __launch_bounds__(256)
void stats2(const float* __restrict__ psum, const float* __restrict__ psq,
            const float* __restrict__ gsc, const float* __restrict__ gbt,
            float* __restrict__ fs, float* __restrict__ bias)
{
    int d = blockIdx.x * 256 + threadIdx.x;
    int b = blockIdx.y;
    float s = 0.f, q = 0.f;
#pragma unroll
    for (int z = 0; z < 4; z++) {
        long o = ((long)(b * 4 + z) << 10) + d;
        s += psum[o];
        q += psq[o];
    }
    float mean = s * (1.0f / SN_);
    float var  = q * (1.0f / SN_) - mean * mean;
    var = fmaxf(var, 0.0f);
    float rstd = rsqrtf(var + EPS_);
    float f = rstd * gsc[d];
    fs[(long)b * DN_ + d]   = f;
    bias[(long)b * DN_ + d] = gbt[d] - mean * f;
}

// ---------------- normalize: bf16 y -> fp32 out ----------------
__global__ __launch_bounds__(256)
void norm_k(const ushort* __restrict__ yb, const float* __restrict__ fs,
            const float* __restrict__ bias, float* __restrict__ out)
{
    long i = ((long)blockIdx.x * 256 + threadIdx.x) * 8;
    int d = (int)(i & (DN_ - 1));
    int b = (int)(i >> 20);
    ushort8 v = *(const ushort8*)&yb[i];
    long o = (long)b * DN_ + d;
    float4 f0 = *(const float4*)&fs[o];
    float4 f1 = *(const float4*)&fs[o + 4];
    float4 b0 = *(const float4*)&bias[o];
    float4 b1 = *(const float4*)&bias[o + 4];
    float4 o0, o1;
    o0.x = __uint_as_float((unsigned)v[0] << 16) * f0.x + b0.x;
    o0.y = __uint_as_float((unsigned)v[1] << 16) * f0.y + b0.y;
    o0.z = __uint_as_float((unsigned)v[2] << 16) * f0.z + b0.z;
    o0.w = __uint_as_float((unsigned)v[3] << 16) * f0.w + b0.w;
    o1.x = __uint_as_float((unsigned)v[4] << 16) * f1.x + b1.x;
    o1.y = __uint_as_float((unsigned)v[5] << 16) * f1.y + b1.y;
    o1.z = __uint_as_float((unsigned)v[6] << 16) * f1.z + b1.z;
    o1.w = __uint_as_float((unsigned)v[7] << 16) * f1.w + b1.w;
    *(float4*)&out[i]     = o0;
    *(float4*)&out[i + 4] = o1;
}

extern "C" void kernel_launch(void* const* d_in, const int* in_sizes, int n_in,
                              void* d_out, int out_size, void* d_ws, size_t ws_size,
                              hipStream_t stream)
{
    const float* x   = (const float*)d_in[0];
    const float* Wq  = (const float*)d_in[1];
    const float* Wk  = (const float*)d_in[2];
    const float* Wv  = (const float*)d_in[3];
    const float* gsc = (const float*)d_in[4];
    const float* gbt = (const float*)d_in[5];
    float* out = (float*)d_out;

    const long SD = (long)SN_ * DN_;
    const long DD = (long)DN_ * DN_;
    const size_t MB32 = (size_t)SD * BATCH_ * sizeof(ushort);  // 32 MiB

    char* ws = (char*)d_ws;
    ushort* xb  = (ushort*)(ws);            // x bf16; reused as yb after projs
    ushort* Qp  = (ushort*)(ws + 1 * MB32);
    ushort* Kt  = (ushort*)(ws + 2 * MB32);
    ushort* Vt  = (ushort*)(ws + 3 * MB32);
    ushort* Mt  = (ushort*)(ws + 4 * MB32);
    ushort* Wct = (ushort*)(ws + 5 * MB32);                       // [3072][1024] bf16
    float*  psum = (float*)(ws + 5 * MB32 + (6u << 20));          // [64][1024]
    float*  psq  = (float*)(ws + 5 * MB32 + (6u << 20) + (1u << 18));
    float*  fs   = (float*)(ws + 5 * MB32 + (6u << 20) + (2u << 18));
    float*  bias = (float*)(ws + 5 * MB32 + (6u << 20) + (2u << 18) + (1u << 16));
    ushort* yb  = xb;

    const float lgf = (float)log2(0.96875);  // log2(gamma)

    dim3 blk(256);
    dim3 gproj(12, 64);     // N=3072/256, M=16384/256  (768 blocks)
    dim3 gmt(4, 4, 16);     // per-batch 1024x1024      (256 blocks)
    dim3 gy(4, 64);         // N=1024/256, M=16384/256  (256 blocks)

    // prepass
    conv_x_k<<<dim3(8192), blk, 0, stream>>>(x, xb);
    wt_k<<<dim3(32, 32), blk, 0, stream>>>(Wq, Wct);
    wt_k<<<dim3(32, 32), blk, 0, stream>>>(Wk, Wct + 1024 * 1024);
    wt_k<<<dim3(32, 32), blk, 0, stream>>>(Wv, Wct + 2 * 1024 * 1024);

    // merged projections: Q' (scale gamma^s), K't (transp, gamma^-s), V't (transp)
    gemm_bf<6><<<gproj, blk, 0, stream>>>(xb, Wct, Qp, Kt, Vt,
                                          nullptr, nullptr,
                                          0, 0, 0, SD, lgf);
    // Mt = V't x Kt(B^T) = M^T   [B][D][D] bf16
    gemm_bf<4><<<gmt, blk, 0, stream>>>(Vt, Kt, Mt, nullptr, nullptr,
                                        nullptr, nullptr,
                                        SD, SD, 0, DD, 0.0f);
    // y = Q' x Mt(B^T per batch) -> bf16 yb + fused column stats
    gemm_bf<5><<<gy, blk, 0, stream>>>(Qp, Mt, yb, nullptr, nullptr,
                                       psum, psq,
                                       0, 0, DD, 0, 0.0f);

    // GroupNorm finalize + apply
    stats2<<<dim3(4, 16), blk, 0, stream>>>(psum, psq, gsc, gbt, fs, bias);
    norm_k<<<dim3(8192), blk, 0, stream>>>(yb, fs, bias, out);
}

// Round 11
// 228.697 us; speedup vs baseline: 1.0594x; 1.0564x over previous
//
#include <hip/hip_runtime.h>
#include <cmath>

#define BATCH_ 16
#define SN_ 1024
#define DN_ 1024

constexpr float EPS_ = 1e-3f;

typedef unsigned short ushort;
typedef __attribute__((ext_vector_type(8))) short short8;
typedef __attribute__((ext_vector_type(8))) unsigned short ushort8;
typedef __attribute__((ext_vector_type(4))) float f32x4;

__device__ __forceinline__ ushort f2b(float f) {
    unsigned u = __float_as_uint(f);
    unsigned r = (u + 0x7fffu + ((u >> 16) & 1u)) >> 16;
    return (ushort)r;
}

__device__ __forceinline__ void gload16(const void* g, void* l) {
    __builtin_amdgcn_global_load_lds(
        (const __attribute__((address_space(1))) void*)g,
        (__attribute__((address_space(3))) void*)l, 16, 0, 0);
}

#define SCHED0 __builtin_amdgcn_sched_barrier(0)
#define BAR do { __builtin_amdgcn_s_barrier(); asm volatile("" ::: "memory"); } while (0)
#define WLG0 do { asm volatile("s_waitcnt lgkmcnt(0)" ::: "memory"); SCHED0; } while (0)
#define MFMA16(a, b, c) __builtin_amdgcn_mfma_f32_16x16x32_bf16(a, b, c, 0, 0, 0)

// ---------------------------------------------------------------------------
// bf16 MFMA GEMM — m201-style 8-phase counted-vmcnt schedule.
// 256x256 tile, BK=64, 512 thr (8 waves, 2Mx4N, per-wave 128x64 output),
// v_mfma_f32_16x16x32_bf16 (acc 8x4 f32x4 = 128 VGPR), double-buffered
// 128 KiB LDS, 256-B physical-row pair-packed swizzle (r8-verified):
//   g = row>>1: byte = (g>>6)*16384 + (g&63)*256 + slot*16,
//   slot = ((c) | 8*(row&1)) ^ (g&15),   c = 16B chunk index (k/8)
// 4 phases per K-tile, each: {ds_read frag subtile || stage 1 half-tile
// (2 gload_lds) -> s_barrier -> lgkmcnt(0) -> setprio+16 MFMA -> s_barrier}.
// Phase reads: p0: A-mh0(8)+B-nh0(4); p1: B-nh1(4); p2: A-mh1(8); p3: 0.
// Staging ring: during kt stage h1,h2,h3 of kt+1 (buf^1) at p0,p1,p2 and
// h0 of kt+2 (current buf — race-free: issued after p2-end barrier, when all
// LDS reads of this tile are drained) at p3. vmcnt(2) at p3 (never 0 in the
// main loop): forces all of kt+1's data landed, leaves h0(kt+2) in flight.
// A row-major [M][K], B in B^T layout [N][K], K = 1024.
// MODE 4: bf16 out plain (Mt)
// MODE 5: bf16 out + per-block column sum/sumsq -> psum/psq[by][1024]  (y)
// MODE 6: merged projections, 3-way epilogue by n-block:
//         which=0 -> Qp (bf16, row-scale gamma^s)
//         which=1 -> Kt (bf16, transposed, scale gamma^-s)
//         which=2 -> Vt (bf16, transposed)
// ---------------------------------------------------------------------------
template<int MODE>
__global__ __launch_bounds__(512, 2)
void gemm_bf(const ushort* __restrict__ A0p, const ushort* __restrict__ B0p,
             void* __restrict__ C0, void* __restrict__ C1, void* __restrict__ C2,
             float* __restrict__ psum, float* __restrict__ psq,
             long sA, long sB, long sBm, long sC, float coef)
{
    __shared__ __align__(16) char lds[131072];  // 2 bufs x (A 32K + B 32K)

    // ---- bijective XCD swizzle (all grids are multiples of 8 blocks) ----
    const int gx = gridDim.x, gy = gridDim.y;
    int lid   = blockIdx.x + gx * (blockIdx.y + gy * blockIdx.z);
    int total = gx * gy * gridDim.z;
    int swz   = (lid & 7) * (total >> 3) + (lid >> 3);
    int bx = swz % gx;
    int rest = swz / gx;
    int by = rest % gy;
    int bz = rest / gy;

    const int m0 = by * 256, n0 = bx * 256;
    const ushort* A  = A0p + (long)bz * sA;
    const ushort* Bp = B0p + (long)bz * sB + (long)(m0 >> 10) * sBm;

    const int t = threadIdx.x;
    const int l = t & 63, w = t >> 6;
    const int wr = w >> 2, wc = w & 3;    // wave grid 2M x 4N
    const int lc  = l & 15;               // row/col lane within fragment
    const int chi = l >> 4;               // k-chunk lane part (0..3)
    const int par8 = (l & 1) * 8;         // row-parity slot offset

    // ---- per-lane fragment address bases (byte offsets inside a buffer) ----
    int baseA[8], xorA[8], baseB[4], xorB[4];
#pragma unroll
    for (int mf = 0; mf < 8; ++mf) {
        int r = wr * 128 + mf * 16 + lc, g = r >> 1;
        baseA[mf] = (g >> 6) * 16384 + (g & 63) * 256;
        xorA[mf]  = g & 15;
    }
#pragma unroll
    for (int nf = 0; nf < 4; ++nf) {
        int r = wc * 64 + nf * 16 + lc, g = r >> 1;
        baseB[nf] = 32768 + (g >> 6) * 16384 + (g & 63) * 256;
        xorB[nf]  = g & 15;
    }
    const int ck0 = chi | par8;           // slot pre-xor, k-step 0
    const int ck1 = (chi + 4) | par8;     // slot pre-xor, k-step 1

    // ---- staging: thread t writes 16B at linear LDS t*16 within an 8KB
    //      issue; global source pre-swizzled per the prow-pair mapping.
    const int su = (t & 15) ^ ((t >> 4) & 15);
    const int sc = su & 7;
    const int srow = 2 * (t >> 4) + (su >> 3);
    const ushort* gA = A  + (long)(m0 + srow) * 1024 + sc * 8;
    const ushort* gB = Bp + (long)(n0 + srow) * 1024 + sc * 8;
    char* lA = lds + t * 16;
    char* lB = lds + 32768 + t * 16;

    // half h of a K-tile: rows h*128..h*128+127, 16KB, 2 issues of 8KB
#define STAGE_A(h, k0, bo_) do { \
    gload16(gA + (long)(h) * 131072 + (k0), lA + (bo_) + (h) * 16384); \
    gload16(gA + (long)(h) * 131072 + 65536 + (k0), lA + (bo_) + (h) * 16384 + 8192); } while (0)
#define STAGE_B(h, k0, bo_) do { \
    gload16(gB + (long)(h) * 131072 + (k0), lB + (bo_) + (h) * 16384); \
    gload16(gB + (long)(h) * 131072 + 65536 + (k0), lB + (bo_) + (h) * 16384 + 8192); } while (0)

#define RDA(S, mh) do { \
    _Pragma("unroll") for (int mf_ = 0; mf_ < 4; ++mf_) { \
        S[mf_][0] = *(const short8*)(lds + bo + baseA[(mh)*4+mf_] + ((ck0 ^ xorA[(mh)*4+mf_]) << 4)); \
        S[mf_][1] = *(const short8*)(lds + bo + baseA[(mh)*4+mf_] + ((ck1 ^ xorA[(mh)*4+mf_]) << 4)); } } while (0)
#define RDB(S, nh) do { \
    _Pragma("unroll") for (int nf_ = 0; nf_ < 2; ++nf_) { \
        S[nf_][0] = *(const short8*)(lds + bo + baseB[(nh)*2+nf_] + ((ck0 ^ xorB[(nh)*2+nf_]) << 4)); \
        S[nf_][1] = *(const short8*)(lds + bo + baseB[(nh)*2+nf_] + ((ck1 ^ xorB[(nh)*2+nf_]) << 4)); } } while (0)

#define MPH(mh, nh, SA_, SB_) do { \
    __builtin_amdgcn_s_setprio(1); \
    _Pragma("unroll") for (int ks_ = 0; ks_ < 2; ++ks_) \
    _Pragma("unroll") for (int mf_ = 0; mf_ < 4; ++mf_) \
    _Pragma("unroll") for (int nf_ = 0; nf_ < 2; ++nf_) \
        acc[(mh)*4+mf_][(nh)*2+nf_] = MFMA16(SA_[mf_][ks_], SB_[nf_][ks_], \
                                             acc[(mh)*4+mf_][(nh)*2+nf_]); \
    __builtin_amdgcn_s_setprio(0); } while (0)

    f32x4 acc[8][4] = {};
    short8 Af0[4][2], Af1[4][2], Bf0[2][2], Bf1[2][2];

    // ---- prologue: stage K-tile 0 fully (buf0) + h0 of K-tile 1 (buf1) ----
    STAGE_A(0, 0, 0); STAGE_A(1, 0, 0); STAGE_B(0, 0, 0); STAGE_B(1, 0, 0);
    STAGE_A(0, 64, 65536);
    SCHED0;
    asm volatile("s_waitcnt vmcnt(2)" ::: "memory");
    BAR;

    for (int kt = 0; kt < 16; ++kt) {
        const int bo = (kt & 1) << 16;
        const int bn = bo ^ 65536;
        const int k1 = (kt + 1) << 6;
        const int k2 = (kt + 2) << 6;

        // ---- phase 0: A-mh0 (8) + B-nh0 (4); stage h1(kt+1) = A-half1 ----
        RDA(Af0, 0); RDB(Bf0, 0);
        if (kt < 15) STAGE_A(1, k1, bn);
        asm volatile("s_waitcnt lgkmcnt(8)" ::: "memory");
        BAR; WLG0;
        MPH(0, 0, Af0, Bf0);
        SCHED0; BAR;

        // ---- phase 1: B-nh1 (4); stage h2(kt+1) = B-half0 ----
        RDB(Bf1, 1);
        if (kt < 15) STAGE_B(0, k1, bn);
        BAR; WLG0;
        MPH(0, 1, Af0, Bf1);
        SCHED0; BAR;

        // ---- phase 2: A-mh1 (8); stage h3(kt+1) = B-half1 ----
        RDA(Af1, 1);
        if (kt < 15) STAGE_B(1, k1, bn);
        BAR; WLG0;
        MPH(1, 0, Af1, Bf0);
        SCHED0; BAR;

        // ---- phase 3: no reads; stage h0(kt+2) = A-half0 into CURRENT buf
        //      (safe: issued after p2-end barrier = all reads of bo drained);
        //      counted vmcnt(2) — h0(kt+2) stays in flight across boundary ----
        if (kt < 14) {
            STAGE_A(0, k2, bo);
            SCHED0;
            asm volatile("s_waitcnt vmcnt(2)" ::: "memory");
        } else {
            asm volatile("s_waitcnt vmcnt(0)" ::: "memory");
        }
        BAR;
        MPH(1, 1, Af1, Bf1);
        SCHED0; BAR;
    }

    // C/D 16x16 layout: col = l&15, row = (l>>4)*4 + reg   [m89-verified]
    // ---------------- epilogues ----------------
    if constexpr (MODE == 4) {
        ushort* C = (ushort*)C0 + (long)bz * sC;
#pragma unroll
        for (int mf = 0; mf < 8; ++mf)
#pragma unroll
            for (int q = 0; q < 4; ++q) {
                int row = m0 + wr * 128 + mf * 16 + chi * 4 + q;
#pragma unroll
                for (int nf = 0; nf < 4; ++nf)
                    C[(long)row * 1024 + n0 + wc * 64 + nf * 16 + lc] =
                        f2b(acc[mf][nf][q]);
            }
    } else if constexpr (MODE == 5) {
        // bf16 y out + per-block column sums/sumsq (fused GroupNorm stats)
        ushort* C = (ushort*)C0;
        float cs[4] = {0.f, 0.f, 0.f, 0.f}, cq[4] = {0.f, 0.f, 0.f, 0.f};
#pragma unroll
        for (int mf = 0; mf < 8; ++mf)
#pragma unroll
            for (int q = 0; q < 4; ++q) {
                int row = m0 + wr * 128 + mf * 16 + chi * 4 + q;
#pragma unroll
                for (int nf = 0; nf < 4; ++nf) {
                    float v = acc[mf][nf][q];
                    cs[nf] += v; cq[nf] += v * v;
                    C[(long)row * 1024 + n0 + wc * 64 + nf * 16 + lc] = f2b(v);
                }
            }
        float* S4 = (float*)lds;            // [256 cols][8]
        float* Q4 = (float*)(lds + 8192);
        {
            int idx = wr * 4 + chi;
#pragma unroll
            for (int nf = 0; nf < 4; ++nf) {
                int ci = wc * 64 + nf * 16 + lc;
                S4[ci * 8 + idx] = cs[nf];
                Q4[ci * 8 + idx] = cq[nf];
            }
        }
        __syncthreads();
        if (t < 256) {
            float s = 0.f, q = 0.f;
#pragma unroll
            for (int z = 0; z < 8; ++z) { s += S4[t * 8 + z]; q += Q4[t * 8 + z]; }
            psum[(long)by * 1024 + n0 + t] = s;
            psq [(long)by * 1024 + n0 + t] = q;
        }
    } else {
        // MODE 6: merged projections
        const int which = n0 >> 10;       // 0=Q, 1=K, 2=V
        const int nq = n0 & 1023;
        if (which == 0) {
            ushort* C = (ushort*)C0;
#pragma unroll
            for (int mf = 0; mf < 8; ++mf)
#pragma unroll
                for (int q = 0; q < 4; ++q) {
                    int row = m0 + wr * 128 + mf * 16 + chi * 4 + q;
                    float s = exp2f(coef * (float)(row & 1023));
#pragma unroll
                    for (int nf = 0; nf < 4; ++nf)
                        C[(long)row * 1024 + nq + wc * 64 + nf * 16 + lc] =
                            f2b(acc[mf][nf][q] * s);
                }
        } else {
            // transposed store via LDS bounce (slot = (rm>>3) ^ (cn&31)),
            // fully coalesced ushort8 readout. out[b][d][s]
            ushort* Tl = (ushort*)lds;
            const int bb = m0 >> 10;          // batch index
            const int ms = m0 & 1023;         // s-offset within batch
            ushort* Ct = (ushort*)((which == 1) ? C1 : C2) + (long)bb * sC;
            const float cf = (which == 1) ? -coef : 0.0f;
            __syncthreads();
#pragma unroll
            for (int mf = 0; mf < 8; ++mf)
#pragma unroll
                for (int q = 0; q < 4; ++q) {
                    int rm = wr * 128 + mf * 16 + chi * 4 + q;
                    float s = exp2f(cf * (float)(ms + rm));
#pragma unroll
                    for (int nf = 0; nf < 4; ++nf) {
                        int cn = wc * 64 + nf * 16 + lc;
                        int p  = (rm >> 3) ^ (cn & 31);
                        Tl[cn * 256 + p * 8 + (rm & 7)] = f2b(acc[mf][nf][q] * s);
                    }
                }
            __syncthreads();
#pragma unroll
            for (int it = 0; it < 16; ++it) {
                int cn = (t >> 5) + it * 16;
                int ch = t & 31;
                int p  = ch ^ (cn & 31);
                ushort8 v = *(const ushort8*)&Tl[cn * 256 + p * 8];
                *(ushort8*)&Ct[(long)(nq + cn) * 1024 + ms + ch * 8] = v;
            }
        }
    }
#undef STAGE_A
#undef STAGE_B
#undef RDA
#undef RDB
#undef MPH
}

// ---------------- prepass: fp32 -> bf16 convert ----------------
__global__ __launch_bounds__(256)
void conv_x_k(const float* __restrict__ x, ushort* __restrict__ xb)
{
    long i = ((long)blockIdx.x * 256 + threadIdx.x) * 8;
    float4 a = *(const float4*)&x[i];
    float4 b = *(const float4*)&x[i + 4];
    ushort8 v;
    v[0] = f2b(a.x); v[1] = f2b(a.y); v[2] = f2b(a.z); v[3] = f2b(a.w);
    v[4] = f2b(b.x); v[5] = f2b(b.y); v[6] = f2b(b.z); v[7] = f2b(b.w);
    *(ushort8*)&xb[i] = v;
}

// ---------------- prepass: weight transpose + convert ----------------
__global__ __launch_bounds__(256)
void wt_k(const float* __restrict__ W, ushort* __restrict__ Wt)
{
    __shared__ float Tl[32][33];
    int tx = threadIdx.x & 31, ty = threadIdx.x >> 5;
    int c0 = blockIdx.x * 32, r0 = blockIdx.y * 32;
#pragma unroll
    for (int i = 0; i < 4; i++)
        Tl[ty + 8 * i][tx] = W[(long)(r0 + ty + 8 * i) * 1024 + c0 + tx];
    __syncthreads();
#pragma unroll
    for (int i = 0; i < 4; i++)
        Wt[(long)(c0 + ty + 8 * i) * 1024 + r0 + tx] = f2b(Tl[tx][ty + 8 * i]);
}

// ---------------- GroupNorm: finalize stats -> fused scale/bias ----------------
__global__ __launch_bounds__(256)
void stats2(const float* __restrict__ psum, const float* __restrict__ psq,
            const float* __restrict__ gsc, const float* __restrict__ gbt,
            float* __restrict__ fs, float* __restrict__ bias)
{
    int d = blockIdx.x * 256 + threadIdx.x;
    int b = blockIdx.y;
    float s = 0.f, q = 0.f;
#pragma unroll
    for (int z = 0; z < 4; z++) {
        long o = ((long)(b * 4 + z) << 10) + d;
        s += psum[o];
        q += psq[o];
    }
    float mean = s * (1.0f / SN_);
    float var  = q * (1.0f / SN_) - mean * mean;
    var = fmaxf(var, 0.0f);
    float rstd = rsqrtf(var + EPS_);
    float f = rstd * gsc[d];
    fs[(long)b * DN_ + d]   = f;
    bias[(long)b * DN_ + d] = gbt[d] - mean * f;
}

// ---------------- normalize: bf16 y -> fp32 out ----------------
__global__ __launch_bounds__(256)
void norm_k(const ushort* __restrict__ yb, const float* __restrict__ fs,
            const float* __restrict__ bias, float* __restrict__ out)
{
    long i = ((long)blockIdx.x * 256 + threadIdx.x) * 8;
    int d = (int)(i & (DN_ - 1));
    int b = (int)(i >> 20);
    ushort8 v = *(const ushort8*)&yb[i];
    long o = (long)b * DN_ + d;
    float4 f0 = *(const float4*)&fs[o];
    float4 f1 = *(const float4*)&fs[o + 4];
    float4 b0 = *(const float4*)&bias[o];
    float4 b1 = *(const float4*)&bias[o + 4];
    float4 o0, o1;
    o0.x = __uint_as_float((unsigned)v[0] << 16) * f0.x + b0.x;
    o0.y = __uint_as_float((unsigned)v[1] << 16) * f0.y + b0.y;
    o0.z = __uint_as_float((unsigned)v[2] << 16) * f0.z + b0.z;
    o0.w = __uint_as_float((unsigned)v[3] << 16) * f0.w + b0.w;
    o1.x = __uint_as_float((unsigned)v[4] << 16) * f1.x + b1.x;
    o1.y = __uint_as_float((unsigned)v[5] << 16) * f1.y + b1.y;
    o1.z = __uint_as_float((unsigned)v[6] << 16) * f1.z + b1.z;
    o1.w = __uint_as_float((unsigned)v[7] << 16) * f1.w + b1.w;
    *(float4*)&out[i]     = o0;
    *(float4*)&out[i + 4] = o1;
}

extern "C" void kernel_launch(void* const* d_in, const int* in_sizes, int n_in,
                              void* d_out, int out_size, void* d_ws, size_t ws_size,
                              hipStream_t stream)
{
    const float* x   = (const float*)d_in[0];
    const float* Wq  = (const float*)d_in[1];
    const float* Wk  = (const float*)d_in[2];
    const float* Wv  = (const float*)d_in[3];
    const float* gsc = (const float*)d_in[4];
    const float* gbt = (const float*)d_in[5];
    float* out = (float*)d_out;

    const long SD = (long)SN_ * DN_;
    const long DD = (long)DN_ * DN_;
    const size_t MB32 = (size_t)SD * BATCH_ * sizeof(ushort);  // 32 MiB

    char* ws = (char*)d_ws;
    ushort* xb  = (ushort*)(ws);            // x bf16; reused as yb after projs
    ushort* Qp  = (ushort*)(ws + 1 * MB32);
    ushort* Kt  = (ushort*)(ws + 2 * MB32);
    ushort* Vt  = (ushort*)(ws + 3 * MB32);
    ushort* Mt  = (ushort*)(ws + 4 * MB32);
    ushort* Wct = (ushort*)(ws + 5 * MB32);                       // [3072][1024] bf16
    float*  psum = (float*)(ws + 5 * MB32 + (6u << 20));          // [64][1024]
    float*  psq  = (float*)(ws + 5 * MB32 + (6u << 20) + (1u << 18));
    float*  fs   = (float*)(ws + 5 * MB32 + (6u << 20) + (2u << 18));
    float*  bias = (float*)(ws + 5 * MB32 + (6u << 20) + (2u << 18) + (1u << 16));
    ushort* yb  = xb;

    const float lgf = (float)log2(0.96875);  // log2(gamma)

    dim3 blk512(512);
    dim3 blk(256);
    dim3 gproj(12, 64);     // N=3072/256, M=16384/256  (768 blocks)
    dim3 gmt(4, 4, 16);     // per-batch 1024x1024      (256 blocks)
    dim3 gy(4, 64);         // N=1024/256, M=16384/256  (256 blocks)

    // prepass
    conv_x_k<<<dim3(8192), blk, 0, stream>>>(x, xb);
    wt_k<<<dim3(32, 32), blk, 0, stream>>>(Wq, Wct);
    wt_k<<<dim3(32, 32), blk, 0, stream>>>(Wk, Wct + 1024 * 1024);
    wt_k<<<dim3(32, 32), blk, 0, stream>>>(Wv, Wct + 2 * 1024 * 1024);

    // merged projections: Q' (scale gamma^s), K't (transp, gamma^-s), V't (transp)
    gemm_bf<6><<<gproj, blk512, 0, stream>>>(xb, Wct, Qp, Kt, Vt,
                                             nullptr, nullptr,
                                             0, 0, 0, SD, lgf);
    // Mt = V't x Kt(B^T) = M^T   [B][D][D] bf16
    gemm_bf<4><<<gmt, blk512, 0, stream>>>(Vt, Kt, Mt, nullptr, nullptr,
                                           nullptr, nullptr,
                                           SD, SD, 0, DD, 0.0f);
    // y = Q' x Mt(B^T per batch) -> bf16 yb + fused column stats
    gemm_bf<5><<<gy, blk512, 0, stream>>>(Qp, Mt, yb, nullptr, nullptr,
                                          psum, psq,
                                          0, 0, DD, 0, 0.0f);

    // GroupNorm finalize + apply
    stats2<<<dim3(4, 16), blk, 0, stream>>>(psum, psq, gsc, gbt, fs, bias);
    norm_k<<<dim3(8192), blk, 0, stream>>>(yb, fs, bias, out);
}

// Round 12
// 225.448 us; speedup vs baseline: 1.0747x; 1.0144x over previous
//
#include <hip/hip_runtime.h>
#include <cmath>

#define BATCH_ 16
#define SN_ 1024
#define DN_ 1024

constexpr float EPS_ = 1e-3f;

typedef unsigned short ushort;
typedef __attribute__((ext_vector_type(8))) short short8;
typedef __attribute__((ext_vector_type(8))) unsigned short ushort8;
typedef __attribute__((ext_vector_type(4))) float f32x4;

__device__ __forceinline__ ushort f2b(float f) {
    unsigned u = __float_as_uint(f);
    unsigned r = (u + 0x7fffu + ((u >> 16) & 1u)) >> 16;
    return (ushort)r;
}

__device__ __forceinline__ void gload16(const void* g, void* l) {
    __builtin_amdgcn_global_load_lds(
        (const __attribute__((address_space(1))) void*)g,
        (__attribute__((address_space(3))) void*)l, 16, 0, 0);
}

#define SCHED0 __builtin_amdgcn_sched_barrier(0)
#define BAR do { __builtin_amdgcn_s_barrier(); asm volatile("" ::: "memory"); } while (0)
#define WLG0 do { asm volatile("s_waitcnt lgkmcnt(0)" ::: "memory"); SCHED0; } while (0)
#define MFMA16(a, b, c) __builtin_amdgcn_mfma_f32_16x16x32_bf16(a, b, c, 0, 0, 0)

// ---------------------------------------------------------------------------
// bf16 MFMA GEMM — m201-style 8-phase counted-vmcnt schedule (r11-verified).
// 256x256 tile, BK=64, 512 thr (8 waves, 2Mx4N, per-wave 128x64 output),
// v_mfma_f32_16x16x32_bf16 (acc 8x4 f32x4 = 128 VGPR), double-buffered
// 128 KiB LDS, 256-B physical-row pair-packed swizzle (r8-verified):
//   g = row>>1: byte = (g>>6)*16384 + (g&63)*256 + slot*16,
//   slot = ((c) | 8*(row&1)) ^ (g&15),   c = 16B chunk index (k/8)
// 4 phases per K-tile, each: {ds_read frag subtile || stage 1 half-tile
// (2 gload_lds) -> s_barrier -> lgkmcnt(0) -> setprio+16 MFMA -> s_barrier}.
// Phase reads: p0: A-mh0(8)+B-nh0(4); p1: B-nh1(4); p2: A-mh1(8); p3: 0.
// Staging ring: during kt stage h1,h2,h3 of kt+1 (buf^1) at p0,p1,p2 and
// h0 of kt+2 (current buf — race-free: issued after p2-end barrier, when all
// LDS reads of this tile are drained) at p3. vmcnt(2) at p3 (never 0 in the
// main loop): forces all of kt+1's data landed, leaves h0(kt+2) in flight.
// A row-major [M][K], B in B^T layout [N][K], K = 1024.
// MODE 4: bf16 out plain (Mt)
// MODE 5: bf16 out + per-block column sum/sumsq -> psum/psq[by][1024]  (y)
// MODE 6: merged projections, 3-way epilogue by n-block:
//         which=0 -> Qp (bf16, row-scale gamma^s)
//         which=1 -> Kt (bf16, transposed, scale gamma^-s)
//         which=2 -> Vt (bf16, transposed)
// ---------------------------------------------------------------------------
template<int MODE>
__global__ __launch_bounds__(512, 2)
void gemm_bf(const ushort* __restrict__ A0p, const ushort* __restrict__ B0p,
             void* __restrict__ C0, void* __restrict__ C1, void* __restrict__ C2,
             float* __restrict__ psum, float* __restrict__ psq,
             long sA, long sB, long sBm, long sC, float coef)
{
    __shared__ __align__(16) char lds[131072];  // 2 bufs x (A 32K + B 32K)

    // ---- bijective XCD swizzle (all grids are multiples of 8 blocks) ----
    const int gx = gridDim.x, gy = gridDim.y;
    int lid   = blockIdx.x + gx * (blockIdx.y + gy * blockIdx.z);
    int total = gx * gy * gridDim.z;
    int swz   = (lid & 7) * (total >> 3) + (lid >> 3);
    int bx = swz % gx;
    int rest = swz / gx;
    int by = rest % gy;
    int bz = rest / gy;

    const int m0 = by * 256, n0 = bx * 256;
    const ushort* A  = A0p + (long)bz * sA;
    const ushort* Bp = B0p + (long)bz * sB + (long)(m0 >> 10) * sBm;

    const int t = threadIdx.x;
    const int l = t & 63, w = t >> 6;
    const int wr = w >> 2, wc = w & 3;    // wave grid 2M x 4N
    const int lc  = l & 15;               // row/col lane within fragment
    const int chi = l >> 4;               // k-chunk lane part (0..3)
    const int par8 = (l & 1) * 8;         // row-parity slot offset

    // ---- per-lane fragment address bases (byte offsets inside a buffer) ----
    int baseA[8], xorA[8], baseB[4], xorB[4];
#pragma unroll
    for (int mf = 0; mf < 8; ++mf) {
        int r = wr * 128 + mf * 16 + lc, g = r >> 1;
        baseA[mf] = (g >> 6) * 16384 + (g & 63) * 256;
        xorA[mf]  = g & 15;
    }
#pragma unroll
    for (int nf = 0; nf < 4; ++nf) {
        int r = wc * 64 + nf * 16 + lc, g = r >> 1;
        baseB[nf] = 32768 + (g >> 6) * 16384 + (g & 63) * 256;
        xorB[nf]  = g & 15;
    }
    const int ck0 = chi | par8;           // slot pre-xor, k-step 0
    const int ck1 = (chi + 4) | par8;     // slot pre-xor, k-step 1

    // ---- staging: thread t writes 16B at linear LDS t*16 within an 8KB
    //      issue; global source pre-swizzled per the prow-pair mapping.
    const int su = (t & 15) ^ ((t >> 4) & 15);
    const int sc = su & 7;
    const int srow = 2 * (t >> 4) + (su >> 3);
    const ushort* gA = A  + (long)(m0 + srow) * 1024 + sc * 8;
    const ushort* gB = Bp + (long)(n0 + srow) * 1024 + sc * 8;
    char* lA = lds + t * 16;
    char* lB = lds + 32768 + t * 16;

    // half h of a K-tile: rows h*128..h*128+127, 16KB, 2 issues of 8KB
#define STAGE_A(h, k0, bo_) do { \
    gload16(gA + (long)(h) * 131072 + (k0), lA + (bo_) + (h) * 16384); \
    gload16(gA + (long)(h) * 131072 + 65536 + (k0), lA + (bo_) + (h) * 16384 + 8192); } while (0)
#define STAGE_B(h, k0, bo_) do { \
    gload16(gB + (long)(h) * 131072 + (k0), lB + (bo_) + (h) * 16384); \
    gload16(gB + (long)(h) * 131072 + 65536 + (k0), lB + (bo_) + (h) * 16384 + 8192); } while (0)

#define RDA(S, mh) do { \
    _Pragma("unroll") for (int mf_ = 0; mf_ < 4; ++mf_) { \
        S[mf_][0] = *(const short8*)(lds + bo + baseA[(mh)*4+mf_] + ((ck0 ^ xorA[(mh)*4+mf_]) << 4)); \
        S[mf_][1] = *(const short8*)(lds + bo + baseA[(mh)*4+mf_] + ((ck1 ^ xorA[(mh)*4+mf_]) << 4)); } } while (0)
#define RDB(S, nh) do { \
    _Pragma("unroll") for (int nf_ = 0; nf_ < 2; ++nf_) { \
        S[nf_][0] = *(const short8*)(lds + bo + baseB[(nh)*2+nf_] + ((ck0 ^ xorB[(nh)*2+nf_]) << 4)); \
        S[nf_][1] = *(const short8*)(lds + bo + baseB[(nh)*2+nf_] + ((ck1 ^ xorB[(nh)*2+nf_]) << 4)); } } while (0)

#define MPH(mh, nh, SA_, SB_) do { \
    __builtin_amdgcn_s_setprio(1); \
    _Pragma("unroll") for (int ks_ = 0; ks_ < 2; ++ks_) \
    _Pragma("unroll") for (int mf_ = 0; mf_ < 4; ++mf_) \
    _Pragma("unroll") for (int nf_ = 0; nf_ < 2; ++nf_) \
        acc[(mh)*4+mf_][(nh)*2+nf_] = MFMA16(SA_[mf_][ks_], SB_[nf_][ks_], \
                                             acc[(mh)*4+mf_][(nh)*2+nf_]); \
    __builtin_amdgcn_s_setprio(0); } while (0)

    f32x4 acc[8][4] = {};
    short8 Af0[4][2], Af1[4][2], Bf0[2][2], Bf1[2][2];

    // ---- prologue: stage K-tile 0 fully (buf0) + h0 of K-tile 1 (buf1) ----
    STAGE_A(0, 0, 0); STAGE_A(1, 0, 0); STAGE_B(0, 0, 0); STAGE_B(1, 0, 0);
    STAGE_A(0, 64, 65536);
    SCHED0;
    asm volatile("s_waitcnt vmcnt(2)" ::: "memory");
    BAR;

    for (int kt = 0; kt < 16; ++kt) {
        const int bo = (kt & 1) << 16;
        const int bn = bo ^ 65536;
        const int k1 = (kt + 1) << 6;
        const int k2 = (kt + 2) << 6;

        // ---- phase 0: A-mh0 (8) + B-nh0 (4); stage h1(kt+1) = A-half1 ----
        RDA(Af0, 0); RDB(Bf0, 0);
        if (kt < 15) STAGE_A(1, k1, bn);
        asm volatile("s_waitcnt lgkmcnt(8)" ::: "memory");
        BAR; WLG0;
        MPH(0, 0, Af0, Bf0);
        SCHED0; BAR;

        // ---- phase 1: B-nh1 (4); stage h2(kt+1) = B-half0 ----
        RDB(Bf1, 1);
        if (kt < 15) STAGE_B(0, k1, bn);
        BAR; WLG0;
        MPH(0, 1, Af0, Bf1);
        SCHED0; BAR;

        // ---- phase 2: A-mh1 (8); stage h3(kt+1) = B-half1 ----
        RDA(Af1, 1);
        if (kt < 15) STAGE_B(1, k1, bn);
        BAR; WLG0;
        MPH(1, 0, Af1, Bf0);
        SCHED0; BAR;

        // ---- phase 3: no reads; stage h0(kt+2) = A-half0 into CURRENT buf
        //      (safe: issued after p2-end barrier = all reads of bo drained);
        //      counted vmcnt(2) — h0(kt+2) stays in flight across boundary ----
        if (kt < 14) {
            STAGE_A(0, k2, bo);
            SCHED0;
            asm volatile("s_waitcnt vmcnt(2)" ::: "memory");
        } else {
            asm volatile("s_waitcnt vmcnt(0)" ::: "memory");
        }
        BAR;
        MPH(1, 1, Af1, Bf1);
        SCHED0; BAR;
    }

    // C/D 16x16 layout: col = l&15, row = (l>>4)*4 + reg   [m89-verified]
    // ---------------- epilogues ----------------
    if constexpr (MODE == 4) {
        ushort* C = (ushort*)C0 + (long)bz * sC;
#pragma unroll
        for (int mf = 0; mf < 8; ++mf)
#pragma unroll
            for (int q = 0; q < 4; ++q) {
                int row = m0 + wr * 128 + mf * 16 + chi * 4 + q;
#pragma unroll
                for (int nf = 0; nf < 4; ++nf)
                    C[(long)row * 1024 + n0 + wc * 64 + nf * 16 + lc] =
                        f2b(acc[mf][nf][q]);
            }
    } else if constexpr (MODE == 5) {
        // bf16 y out + per-block column sums/sumsq (fused GroupNorm stats)
        ushort* C = (ushort*)C0;
        float cs[4] = {0.f, 0.f, 0.f, 0.f}, cq[4] = {0.f, 0.f, 0.f, 0.f};
#pragma unroll
        for (int mf = 0; mf < 8; ++mf)
#pragma unroll
            for (int q = 0; q < 4; ++q) {
                int row = m0 + wr * 128 + mf * 16 + chi * 4 + q;
#pragma unroll
                for (int nf = 0; nf < 4; ++nf) {
                    float v = acc[mf][nf][q];
                    cs[nf] += v; cq[nf] += v * v;
                    C[(long)row * 1024 + n0 + wc * 64 + nf * 16 + lc] = f2b(v);
                }
            }
        float* S4 = (float*)lds;            // [256 cols][8]
        float* Q4 = (float*)(lds + 8192);
        {
            int idx = wr * 4 + chi;
#pragma unroll
            for (int nf = 0; nf < 4; ++nf) {
                int ci = wc * 64 + nf * 16 + lc;
                S4[ci * 8 + idx] = cs[nf];
                Q4[ci * 8 + idx] = cq[nf];
            }
        }
        __syncthreads();
        if (t < 256) {
            float s = 0.f, q = 0.f;
#pragma unroll
            for (int z = 0; z < 8; ++z) { s += S4[t * 8 + z]; q += Q4[t * 8 + z]; }
            psum[(long)by * 1024 + n0 + t] = s;
            psq [(long)by * 1024 + n0 + t] = q;
        }
    } else {
        // MODE 6: merged projections
        const int which = n0 >> 10;       // 0=Q, 1=K, 2=V
        const int nq = n0 & 1023;
        if (which == 0) {
            ushort* C = (ushort*)C0;
#pragma unroll
            for (int mf = 0; mf < 8; ++mf)
#pragma unroll
                for (int q = 0; q < 4; ++q) {
                    int row = m0 + wr * 128 + mf * 16 + chi * 4 + q;
                    float s = exp2f(coef * (float)(row & 1023));
#pragma unroll
                    for (int nf = 0; nf < 4; ++nf)
                        C[(long)row * 1024 + nq + wc * 64 + nf * 16 + lc] =
                            f2b(acc[mf][nf][q] * s);
                }
        } else {
            // transposed store via LDS bounce (slot = (rm>>3) ^ (cn&31)),
            // fully coalesced ushort8 readout. out[b][d][s]
            ushort* Tl = (ushort*)lds;
            const int bb = m0 >> 10;          // batch index
            const int ms = m0 & 1023;         // s-offset within batch
            ushort* Ct = (ushort*)((which == 1) ? C1 : C2) + (long)bb * sC;
            const float cf = (which == 1) ? -coef : 0.0f;
            __syncthreads();
#pragma unroll
            for (int mf = 0; mf < 8; ++mf)
#pragma unroll
                for (int q = 0; q < 4; ++q) {
                    int rm = wr * 128 + mf * 16 + chi * 4 + q;
                    float s = exp2f(cf * (float)(ms + rm));
#pragma unroll
                    for (int nf = 0; nf < 4; ++nf) {
                        int cn = wc * 64 + nf * 16 + lc;
                        int p  = (rm >> 3) ^ (cn & 31);
                        Tl[cn * 256 + p * 8 + (rm & 7)] = f2b(acc[mf][nf][q] * s);
                    }
                }
            __syncthreads();
#pragma unroll
            for (int it = 0; it < 16; ++it) {
                int cn = (t >> 5) + it * 16;
                int ch = t & 31;
                int p  = ch ^ (cn & 31);
                ushort8 v = *(const ushort8*)&Tl[cn * 256 + p * 8];
                *(ushort8*)&Ct[(long)(nq + cn) * 1024 + ms + ch * 8] = v;
            }
        }
    }
#undef STAGE_A
#undef STAGE_B
#undef RDA
#undef RDB
#undef MPH
}

// ---------------- fused prepass: x->bf16 convert + 3x weight transpose ----
// flat grid: blocks 0..8191 convert x (16 Mi elems, 8/thread);
// blocks 8192..11263 transpose+convert Wq/Wk/Wv into Wct[3][1024][1024].
__global__ __launch_bounds__(256)
void prep_k(const float* __restrict__ x, ushort* __restrict__ xb,
            const float* __restrict__ Wq, const float* __restrict__ Wk,
            const float* __restrict__ Wv, ushort* __restrict__ Wct)
{
    int id = blockIdx.x;
    if (id < 8192) {
        long i = ((long)id * 256 + threadIdx.x) * 8;
        float4 a = *(const float4*)&x[i];
        float4 b = *(const float4*)&x[i + 4];
        ushort8 v;
        v[0] = f2b(a.x); v[1] = f2b(a.y); v[2] = f2b(a.z); v[3] = f2b(a.w);
        v[4] = f2b(b.x); v[5] = f2b(b.y); v[6] = f2b(b.z); v[7] = f2b(b.w);
        *(ushort8*)&xb[i] = v;
    } else {
        __shared__ float Tl[32][33];
        int wid = id - 8192;                 // 0..3071
        int sel = wid >> 10;                 // 0=Q, 1=K, 2=V
        const float* W = (sel == 0) ? Wq : (sel == 1 ? Wk : Wv);
        ushort* Wt = Wct + (long)sel * 1024 * 1024;
        int lw = wid & 1023;
        int c0 = (lw & 31) * 32, r0 = (lw >> 5) * 32;
        int tx = threadIdx.x & 31, ty = threadIdx.x >> 5;
#pragma unroll
        for (int i = 0; i < 4; i++)
            Tl[ty + 8 * i][tx] = W[(long)(r0 + ty + 8 * i) * 1024 + c0 + tx];
        __syncthreads();
#pragma unroll
        for (int i = 0; i < 4; i++)
            Wt[(long)(c0 + ty + 8 * i) * 1024 + r0 + tx] = f2b(Tl[tx][ty + 8 * i]);
    }
}

// ---------------- GroupNorm: finalize stats -> fused scale/bias ----------------
__global__ __launch_bounds__(256)
void stats2(const float* __restrict__ psum, const float* __restrict__ psq,
            const float* __restrict__ gsc, const float* __restrict__ gbt,
            float* __restrict__ fs, float* __restrict__ bias)
{
    int d = blockIdx.x * 256 + threadIdx.x;
    int b = blockIdx.y;
    float s = 0.f, q = 0.f;
#pragma unroll
    for (int z = 0; z < 4; z++) {
        long o = ((long)(b * 4 + z) << 10) + d;
        s += psum[o];
        q += psq[o];
    }
    float mean = s * (1.0f / SN_);
    float var  = q * (1.0f / SN_) - mean * mean;
    var = fmaxf(var, 0.0f);
    float rstd = rsqrtf(var + EPS_);
    float f = rstd * gsc[d];
    fs[(long)b * DN_ + d]   = f;
    bias[(long)b * DN_ + d] = gbt[d] - mean * f;
}

// ---------------- normalize: bf16 y -> fp32 out ----------------
__global__ __launch_bounds__(256)
void norm_k(const ushort* __restrict__ yb, const float* __restrict__ fs,
            const float* __restrict__ bias, float* __restrict__ out)
{
    long i = ((long)blockIdx.x * 256 + threadIdx.x) * 8;
    int d = (int)(i & (DN_ - 1));
    int b = (int)(i >> 20);
    ushort8 v = *(const ushort8*)&yb[i];
    long o = (long)b * DN_ + d;
    float4 f0 = *(const float4*)&fs[o];
    float4 f1 = *(const float4*)&fs[o + 4];
    float4 b0 = *(const float4*)&bias[o];
    float4 b1 = *(const float4*)&bias[o + 4];
    float4 o0, o1;
    o0.x = __uint_as_float((unsigned)v[0] << 16) * f0.x + b0.x;
    o0.y = __uint_as_float((unsigned)v[1] << 16) * f0.y + b0.y;
    o0.z = __uint_as_float((unsigned)v[2] << 16) * f0.z + b0.z;
    o0.w = __uint_as_float((unsigned)v[3] << 16) * f0.w + b0.w;
    o1.x = __uint_as_float((unsigned)v[4] << 16) * f1.x + b1.x;
    o1.y = __uint_as_float((unsigned)v[5] << 16) * f1.y + b1.y;
    o1.z = __uint_as_float((unsigned)v[6] << 16) * f1.z + b1.z;
    o1.w = __uint_as_float((unsigned)v[7] << 16) * f1.w + b1.w;
    *(float4*)&out[i]     = o0;
    *(float4*)&out[i + 4] = o1;
}

extern "C" void kernel_launch(void* const* d_in, const int* in_sizes, int n_in,
                              void* d_out, int out_size, void* d_ws, size_t ws_size,
                              hipStream_t stream)
{
    const float* x   = (const float*)d_in[0];
    const float* Wq  = (const float*)d_in[1];
    const float* Wk  = (const float*)d_in[2];
    const float* Wv  = (const float*)d_in[3];
    const float* gsc = (const float*)d_in[4];
    const float* gbt = (const float*)d_in[5];
    float* out = (float*)d_out;

    const long SD = (long)SN_ * DN_;
    const long DD = (long)DN_ * DN_;
    const size_t MB32 = (size_t)SD * BATCH_ * sizeof(ushort);  // 32 MiB

    char* ws = (char*)d_ws;
    ushort* xb  = (ushort*)(ws);            // x bf16; reused as yb after projs
    ushort* Qp  = (ushort*)(ws + 1 * MB32);
    ushort* Kt  = (ushort*)(ws + 2 * MB32);
    ushort* Vt  = (ushort*)(ws + 3 * MB32);
    ushort* Mt  = (ushort*)(ws + 4 * MB32);
    ushort* Wct = (ushort*)(ws + 5 * MB32);                       // [3072][1024] bf16
    float*  psum = (float*)(ws + 5 * MB32 + (6u << 20));          // [64][1024]
    float*  psq  = (float*)(ws + 5 * MB32 + (6u << 20) + (1u << 18));
    float*  fs   = (float*)(ws + 5 * MB32 + (6u << 20) + (2u << 18));
    float*  bias = (float*)(ws + 5 * MB32 + (6u << 20) + (2u << 18) + (1u << 16));
    ushort* yb  = xb;

    const float lgf = (float)log2(0.96875);  // log2(gamma)

    dim3 blk512(512);
    dim3 blk(256);
    dim3 gproj(12, 64);     // N=3072/256, M=16384/256  (768 blocks)
    dim3 gmt(4, 4, 16);     // per-batch 1024x1024      (256 blocks)
    dim3 gy(4, 64);         // N=1024/256, M=16384/256  (256 blocks)

    // fused prepass: x conversion + 3 weight transposes in one dispatch
    prep_k<<<dim3(11264), blk, 0, stream>>>(x, xb, Wq, Wk, Wv, Wct);

    // merged projections: Q' (scale gamma^s), K't (transp, gamma^-s), V't (transp)
    gemm_bf<6><<<gproj, blk512, 0, stream>>>(xb, Wct, Qp, Kt, Vt,
                                             nullptr, nullptr,
                                             0, 0, 0, SD, lgf);
    // Mt = V't x Kt(B^T) = M^T   [B][D][D] bf16
    gemm_bf<4><<<gmt, blk512, 0, stream>>>(Vt, Kt, Mt, nullptr, nullptr,
                                           nullptr, nullptr,
                                           SD, SD, 0, DD, 0.0f);
    // y = Q' x Mt(B^T per batch) -> bf16 yb + fused column stats
    gemm_bf<5><<<gy, blk512, 0, stream>>>(Qp, Mt, yb, nullptr, nullptr,
                                          psum, psq,
                                          0, 0, DD, 0, 0.0f);

    // GroupNorm finalize + apply
    stats2<<<dim3(4, 16), blk, 0, stream>>>(psum, psq, gsc, gbt, fs, bias);
    norm_k<<<dim3(8192), blk, 0, stream>>>(yb, fs, bias, out);
}